// Round 16
// baseline (134.498 us; speedup 1.0000x reference)
//
#include <hip/hip_runtime.h>

constexpr int HH = 100;
constexpr int WW = 100;
constexpr int NH = 8;
constexpr int NP = 4;
constexpr int B  = 4;
constexpr int Q  = HH * WW;   // 10000
constexpr int S  = Q;
constexpr int K  = 256;
constexpr int DH = 32;
constexpr int M  = B * Q;     // 40000
constexpr int NTILES = M / 32; // 1250 (out_proj)
constexpr int T16 = M / 16;    // 2500 (stage1 16-row tiles)

typedef __attribute__((ext_vector_type(8))) short short8;
typedef __attribute__((ext_vector_type(4))) float f32x4;

struct __align__(8) ushort4p { unsigned short x, y, z, w; };

__device__ inline unsigned short f2bf(float f) {
    unsigned u = __builtin_bit_cast(unsigned, f);
    u += 0x7fffu + ((u >> 16) & 1u);          // RNE
    return (unsigned short)(u >> 16);
}
__device__ inline float bf2f(unsigned short h) {
    return __builtin_bit_cast(float, ((unsigned)h) << 16);
}
__device__ inline unsigned short f2h(float f) {
    _Float16 h = (_Float16)f;
    return __builtin_bit_cast(unsigned short, h);
}
__device__ inline float h2f(unsigned short u) {
    return (float)__builtin_bit_cast(_Float16, u);
}

// LDS bf16 tile helpers (16B-chunk XOR swizzle: chunk ^= row&7).
__device__ inline void lds_st16s(short* base, int row, int stride, int kcol, short8 v) {
    *reinterpret_cast<short8*>(&base[row * stride + (kcol ^ ((row & 7) << 3))]) = v;
}
__device__ inline short8 lds_ld16s(const short* base, int row, int stride, int kcol) {
    return *reinterpret_cast<const short8*>(&base[row * stride + (kcol ^ ((row & 7) << 3))]);
}

__device__ inline short8 cvt8(float4 a, float4 b) {
    short8 r;
    r[0] = (short)f2bf(a.x); r[1] = (short)f2bf(a.y);
    r[2] = (short)f2bf(a.z); r[3] = (short)f2bf(a.w);
    r[4] = (short)f2bf(b.x); r[5] = (short)f2bf(b.y);
    r[6] = (short)f2bf(b.z); r[7] = (short)f2bf(b.w);
    return r;
}

// ---------------------------------------------------------------------------
// Stage 1 (BARRIER-FREE steady state): value proj + off/attn proj.
// 256 blocks x 1024 thr. WEIGHTS live in LDS, staged once (value: 128 KB,
// proj: 48 KB) behind a single __syncthreads. A-tile fragments are loaded
// DIRECTLY global -> registers in native MFMA layout (no ds_write, no
// barriers, no vmcnt coupling). Each wave independently owns 16-row m-tiles
// (stride = total waves) and loops n-chunks reading B-frags from LDS
// (the 0-bank-conflict pattern of rounds 7-10). Swapped MFMA: lane owns
// m = l15, n = nc*16 + l4*4 + r -> one packed 8B store per n-chunk.
//   blocks 0..142   : enc @ W_val^T   -> vflat bf16
//   blocks 143..255 : hidden @ [W_off;W_attn]^T -> proj f16 [M][96]
// ---------------------------------------------------------------------------
__global__ __launch_bounds__(1024) void stage1(
    const float* __restrict__ enc, const float* __restrict__ Wval,
    const float* __restrict__ bval, unsigned short* __restrict__ vflat,
    const float* __restrict__ hidden, const float* __restrict__ Woff,
    const float* __restrict__ Wattn, const float* __restrict__ boff,
    const float* __restrict__ battn, unsigned short* __restrict__ proj)
{
    __shared__ __align__(16) short Bs[256 * 256];   // 131072 B

    const int tid  = threadIdx.x;
    const int lane = tid & 63, w = tid >> 6;
    const int l15  = lane & 15, l4 = lane >> 4;

    constexpr int NV = 143, NJ = 113;

    if (blockIdx.x < NV) {
        // ================ value projection ================
        {   // stage full W_val once, f32 -> bf16 (0-conflict pattern, round 8)
            const int brow = tid >> 2, kb = (tid & 3) * 64;
#pragma unroll
            for (int c = 0; c < 8; ++c) {
                const float* s = &Wval[(size_t)brow * 256 + kb + c * 8];
                lds_st16s(Bs, brow, 256, kb + c * 8,
                          cvt8(*reinterpret_cast<const float4*>(s),
                               *reinterpret_cast<const float4*>(s + 4)));
            }
        }
        __syncthreads();   // the ONLY barrier

        const int nwaves = NV * 16;           // 2288
        for (int t = blockIdx.x * 16 + w; t < T16; t += nwaves) {
            // ---- A-frags: global f32 -> reg bf16, native MFMA layout ----
            const int mrow = t * 16 + l15;
            const float* abase = enc + (size_t)mrow * K;
            short8 areg[8];
#pragma unroll
            for (int ks = 0; ks < 8; ++ks) {
                const float* s = abase + ks * 32 + l4 * 8;
                areg[ks] = cvt8(*reinterpret_cast<const float4*>(s),
                                *reinterpret_cast<const float4*>(s + 4));
            }
            const int b_ = mrow / S, s_ = mrow - b_ * S;   // once per tile
            const size_t obase = ((size_t)b_ * NH) * S + s_;

            // ---- n-chunks: B from LDS, 8 MFMA each, packed store ----
#pragma unroll 4
            for (int nc = 0; nc < 16; ++nc) {
                f32x4 acc = {0.f, 0.f, 0.f, 0.f};
#pragma unroll
                for (int ks = 0; ks < 8; ++ks) {
                    const short8 bb = lds_ld16s(Bs, nc * 16 + l15, 256, ks * 32 + l4 * 8);
                    acc = __builtin_amdgcn_mfma_f32_16x16x32_bf16(bb, areg[ks], acc, 0, 0, 0);
                }
                const int n0 = nc * 16 + l4 * 4;
                const float4 b4 = *reinterpret_cast<const float4*>(&bval[n0]);
                const int h = n0 >> 5, dd0 = n0 & 31;
                ushort4p pk;
                pk.x = f2bf(acc[0] + b4.x);
                pk.y = f2bf(acc[1] + b4.y);
                pk.z = f2bf(acc[2] + b4.z);
                pk.w = f2bf(acc[3] + b4.w);
                *reinterpret_cast<ushort4p*>(
                    &vflat[(obase + (size_t)h * S) * DH + dd0]) = pk;
            }
        }
    } else {
        // ================ off+attn projection ================
        {   // stage [W_off;W_attn] (96x256) once, f32 -> bf16
#pragma unroll
            for (int j = 0; j < 3; ++j) {
                const int ch = tid * 3 + j;        // 0..3071
                const int brow = ch >> 5, kc = (ch & 31) * 8;
                const float* s = (brow < 64)
                    ? &Woff[(size_t)brow * 256 + kc]
                    : &Wattn[(size_t)(brow - 64) * 256 + kc];
                lds_st16s(Bs, brow, 256, kc,
                          cvt8(*reinterpret_cast<const float4*>(s),
                               *reinterpret_cast<const float4*>(s + 4)));
            }
        }
        __syncthreads();

        const int nwaves = NJ * 16;           // 1808
        for (int t = (blockIdx.x - NV) * 16 + w; t < T16; t += nwaves) {
            const int mrow = t * 16 + l15;
            const float* abase = hidden + (size_t)mrow * K;
            short8 areg[8];
#pragma unroll
            for (int ks = 0; ks < 8; ++ks) {
                const float* s = abase + ks * 32 + l4 * 8;
                areg[ks] = cvt8(*reinterpret_cast<const float4*>(s),
                                *reinterpret_cast<const float4*>(s + 4));
            }
            const size_t prow = (size_t)mrow * 96;

#pragma unroll
            for (int nc = 0; nc < 6; ++nc) {
                f32x4 acc = {0.f, 0.f, 0.f, 0.f};
#pragma unroll
                for (int ks = 0; ks < 8; ++ks) {
                    const short8 bb = lds_ld16s(Bs, nc * 16 + l15, 256, ks * 32 + l4 * 8);
                    acc = __builtin_amdgcn_mfma_f32_16x16x32_bf16(bb, areg[ks], acc, 0, 0, 0);
                }
                const int n0 = nc * 16 + l4 * 4;
                const float4 b4 = (n0 < 64)
                    ? *reinterpret_cast<const float4*>(&boff[n0])
                    : *reinterpret_cast<const float4*>(&battn[n0 - 64]);
                ushort4p pk;
                pk.x = f2h(acc[0] + b4.x);
                pk.y = f2h(acc[1] + b4.y);
                pk.z = f2h(acc[2] + b4.z);
                pk.w = f2h(acc[3] + b4.w);
                *reinterpret_cast<ushort4p*>(&proj[prow + n0]) = pk;
            }
        }
    }
}

// ---------------------------------------------------------------------------
// Kernel S: bilinear sampling + attention aggregation (round-10/14 version).
// 4 lanes per (b,h,q) group; lane owns 8 d-elements (16B gathers).
// 64 groups per 256-thread block; 5000 blocks, XCD-swizzled.
// ---------------------------------------------------------------------------
__global__ __launch_bounds__(256) void sample_agg(
    const unsigned short* __restrict__ vflat,  // [B*NH][S][DH] bf16
    const unsigned short* __restrict__ proj,   // [M][96] f16
    const float* __restrict__ ref,             // [M][2]
    unsigned short* __restrict__ tmp)          // [M][256] bf16
{
    const int nblk = gridDim.x;                // 5000, %8 == 0
    const int cpx  = nblk >> 3;
    const int swz  = (blockIdx.x & 7) * cpx + (blockIdx.x >> 3);

    const int lg   = threadIdx.x >> 2;   // 0..63
    const int lane = threadIdx.x & 3;
    const int d0   = lane * 8;

    const int g  = swz * 64 + lg;
    const int q  = g % Q;
    const int bh = g / Q;
    const int b  = bh >> 3;
    const int h  = bh & 7;

    const size_t bq = (size_t)b * Q + q;
    const float refx = ref[bq * 2 + 0];
    const float refy = ref[bq * 2 + 1];
    const unsigned short* pr = proj + bq * 96;

    float l[NP];
#pragma unroll
    for (int p = 0; p < NP; ++p) l[p] = h2f(pr[64 + h * 4 + p]);
    const float mx = fmaxf(fmaxf(l[0], l[1]), fmaxf(l[2], l[3]));
    float e[NP];
    float esum = 0.f;
#pragma unroll
    for (int p = 0; p < NP; ++p) { e[p] = __expf(l[p] - mx); esum += e[p]; }
    const float inv = 1.f / esum;

    const unsigned short* vbase = vflat + (size_t)bh * (S * DH);

    int   cidx[NP][4];
    float cw[NP][4];
#pragma unroll
    for (int p = 0; p < NP; ++p) {
        const float ox = h2f(pr[h * 8 + p * 2 + 0]);
        const float oy = h2f(pr[h * 8 + p * 2 + 1]);
        const float x = fmaf(refx, (float)WW, ox) - 0.5f;
        const float y = fmaf(refy, (float)HH, oy) - 0.5f;
        const float x0f = floorf(x), y0f = floorf(y);
        const float wx1 = x - x0f, wx0 = 1.f - wx1;
        const float wy1 = y - y0f, wy0 = 1.f - wy1;
        const int x0 = (int)x0f, y0 = (int)y0f;
        const bool vx0 = (x0 >= 0) && (x0 < WW);
        const bool vx1 = (x0 + 1 >= 0) && (x0 + 1 < WW);
        const bool vy0 = (y0 >= 0) && (y0 < HH);
        const bool vy1 = (y0 + 1 >= 0) && (y0 + 1 < HH);
        const int xi0 = min(max(x0, 0), WW - 1);
        const int xi1 = min(max(x0 + 1, 0), WW - 1);
        const int yi0 = min(max(y0, 0), HH - 1);
        const int yi1 = min(max(y0 + 1, 0), HH - 1);
        const float ap = e[p] * inv;
        cw[p][0] = ap * wx0 * wy0 * ((vx0 && vy0) ? 1.f : 0.f);
        cw[p][1] = ap * wx1 * wy0 * ((vx1 && vy0) ? 1.f : 0.f);
        cw[p][2] = ap * wx0 * wy1 * ((vx0 && vy1) ? 1.f : 0.f);
        cw[p][3] = ap * wx1 * wy1 * ((vx1 && vy1) ? 1.f : 0.f);
        cidx[p][0] = (yi0 * WW + xi0) * DH + d0;
        cidx[p][1] = (yi0 * WW + xi1) * DH + d0;
        cidx[p][2] = (yi1 * WW + xi0) * DH + d0;
        cidx[p][3] = (yi1 * WW + xi1) * DH + d0;
    }

    float o[8];
#pragma unroll
    for (int j = 0; j < 8; ++j) o[j] = 0.f;
#pragma unroll
    for (int p = 0; p < NP; ++p) {
#pragma unroll
        for (int c = 0; c < 4; ++c) {
            const short8 v = *reinterpret_cast<const short8*>(&vbase[cidx[p][c]]);
            const float wgt = cw[p][c];
#pragma unroll
            for (int j = 0; j < 8; ++j)
                o[j] = fmaf(wgt, bf2f((unsigned short)v[j]), o[j]);
        }
    }

    short8 ov;
#pragma unroll
    for (int j = 0; j < 8; ++j) ov[j] = (short)f2bf(o[j]);
    *reinterpret_cast<short8*>(&tmp[bq * 256 + h * 32 + d0]) = ov;
}

// ---------------------------------------------------------------------------
// Kernel O: out projection (round-14 version: 256 blocks x 1024 thr,
// W in VGPRs, A dbuf in LDS, 1-deep prefetch, __syncthreads per tile,
// swapped-MFMA packed f32x4 stores).
// ---------------------------------------------------------------------------
__global__ __launch_bounds__(1024) void out_proj(
    const unsigned short* __restrict__ tmp, const float* __restrict__ Wo,
    const float* __restrict__ bo, float* __restrict__ out)
{
    __shared__ __align__(16) short As[2][32 * 256];   // 2 x 16 KB

    const int tid  = threadIdx.x;
    const int lane = tid & 63, w = tid >> 6;
    const int l15  = lane & 15, l4 = lane >> 4;
    const int arow = tid >> 5, ak = (tid & 31) * 8;

    const int n = w * 16 + l15;               // lane's weight row
    short8 breg[8];
#pragma unroll
    for (int ks = 0; ks < 8; ++ks) {
        const float* s = &Wo[(size_t)n * K + ks * 32 + l4 * 8];
        breg[ks] = cvt8(*reinterpret_cast<const float4*>(s),
                        *reinterpret_cast<const float4*>(s + 4));
    }
    const int nbase = w * 16 + l4 * 4;        // output n-range after swap
    const float4 bias4 = *reinterpret_cast<const float4*>(&bo[nbase]);

    int t = blockIdx.x;
    short8 sa;
    auto lda = [&](int tt) {
        sa = *reinterpret_cast<const short8*>(&tmp[(size_t)(tt * 32 + arow) * K + ak]);
    };
    lda(t);
    lds_st16s(As[0], arow, 256, ak, sa);
    __syncthreads();
    int cur = 0;
    for (; t < NTILES; t += 256) {
        const bool more = (t + 256 < NTILES);
        if (more) lda(t + 256);

        f32x4 acc0 = {0.f, 0.f, 0.f, 0.f}, acc1 = {0.f, 0.f, 0.f, 0.f};
#pragma unroll
        for (int ks = 0; ks < 8; ++ks) {
            const int kc = ks * 32 + l4 * 8;
            const short8 a0 = lds_ld16s(As[cur], l15, 256, kc);
            const short8 a1 = lds_ld16s(As[cur], 16 + l15, 256, kc);
            acc0 = __builtin_amdgcn_mfma_f32_16x16x32_bf16(breg[ks], a0, acc0, 0, 0, 0);
            acc1 = __builtin_amdgcn_mfma_f32_16x16x32_bf16(breg[ks], a1, acc1, 0, 0, 0);
        }
        const int m0 = t * 32;
        {
            const int m = m0 + l15;
            float4 pv;
            pv.x = acc0[0] + bias4.x; pv.y = acc0[1] + bias4.y;
            pv.z = acc0[2] + bias4.z; pv.w = acc0[3] + bias4.w;
            *reinterpret_cast<float4*>(&out[(size_t)m * K + nbase]) = pv;
        }
        {
            const int m = m0 + 16 + l15;
            float4 pv;
            pv.x = acc1[0] + bias4.x; pv.y = acc1[1] + bias4.y;
            pv.z = acc1[2] + bias4.z; pv.w = acc1[3] + bias4.w;
            *reinterpret_cast<float4*>(&out[(size_t)m * K + nbase]) = pv;
        }
        if (more) lds_st16s(As[cur ^ 1], arow, 256, ak, sa);
        __syncthreads();
        cur ^= 1;
    }
}

// ---------------------------------------------------------------------------
extern "C" void kernel_launch(void* const* d_in, const int* in_sizes, int n_in,
                              void* d_out, int out_size, void* d_ws, size_t ws_size,
                              hipStream_t stream)
{
    const float* hidden = (const float*)d_in[0];
    const float* enc    = (const float*)d_in[1];
    const float* refp   = (const float*)d_in[2];
    const float* W_off  = (const float*)d_in[4];
    const float* b_off  = (const float*)d_in[5];
    const float* W_attn = (const float*)d_in[6];
    const float* b_attn = (const float*)d_in[7];
    const float* W_val  = (const float*)d_in[8];
    const float* b_val  = (const float*)d_in[9];
    const float* W_out  = (const float*)d_in[10];
    const float* b_out  = (const float*)d_in[11];
    float* out = (float*)d_out;

    // workspace (u16 elements): vflat | proj | tmp
    unsigned short* vflat = (unsigned short*)d_ws;     // 10,240,000
    unsigned short* proj  = vflat + (size_t)10240000;  //  3,840,000
    unsigned short* tmp   = proj + (size_t)3840000;    // 10,240,000

    // 1) value proj (143 blocks) + off/attn proj (113 blocks),
    //    weights-in-LDS, barrier-free independent waves
    stage1<<<256, 1024, 0, stream>>>(
        enc, W_val, b_val, vflat, hidden, W_off, W_attn, b_off, b_attn, proj);

    // 2) bilinear sampling + softmax aggregation -> tmp bf16 [M][256]
    sample_agg<<<5000, 256, 0, stream>>>(vflat, proj, refp, tmp);

    // 3) out projection (reg-B persistent, A dbuf, packed f32x4 stores) -> f32
    out_proj<<<256, 1024, 0, stream>>>(tmp, W_out, b_out, out);
}

// Round 17
// 92.627 us; speedup vs baseline: 1.4520x; 1.4520x over previous
//
#include <hip/hip_runtime.h>

constexpr int HH = 100;
constexpr int WW = 100;
constexpr int NH = 8;
constexpr int NP = 4;
constexpr int B  = 4;
constexpr int Q  = HH * WW;   // 10000
constexpr int S  = Q;
constexpr int K  = 256;
constexpr int DH = 32;
constexpr int M  = B * Q;     // 40000
constexpr int NTILES = M / 32; // 1250

typedef __attribute__((ext_vector_type(8))) short short8;
typedef __attribute__((ext_vector_type(4))) float f32x4;

struct __align__(8) ushort4p { unsigned short x, y, z, w; };

__device__ inline unsigned short f2bf(float f) {
    unsigned u = __builtin_bit_cast(unsigned, f);
    u += 0x7fffu + ((u >> 16) & 1u);          // RNE
    return (unsigned short)(u >> 16);
}
__device__ inline float bf2f(unsigned short h) {
    return __builtin_bit_cast(float, ((unsigned)h) << 16);
}
__device__ inline unsigned short f2h(float f) {
    _Float16 h = (_Float16)f;
    return __builtin_bit_cast(unsigned short, h);
}
__device__ inline float h2f(unsigned short u) {
    return (float)__builtin_bit_cast(_Float16, u);
}

// LDS bf16 tile helpers (16B-chunk XOR swizzle: chunk ^= row&7).
__device__ inline void lds_st16s(short* base, int row, int stride, int kcol, short8 v) {
    *reinterpret_cast<short8*>(&base[row * stride + (kcol ^ ((row & 7) << 3))]) = v;
}
__device__ inline short8 lds_ld16s(const short* base, int row, int stride, int kcol) {
    return *reinterpret_cast<const short8*>(&base[row * stride + (kcol ^ ((row & 7) << 3))]);
}

__device__ inline short8 cvt8(float4 a, float4 b) {
    short8 r;
    r[0] = (short)f2bf(a.x); r[1] = (short)f2bf(a.y);
    r[2] = (short)f2bf(a.z); r[3] = (short)f2bf(a.w);
    r[4] = (short)f2bf(b.x); r[5] = (short)f2bf(b.y);
    r[6] = (short)f2bf(b.z); r[7] = (short)f2bf(b.w);
    return r;
}

// ---------------------------------------------------------------------------
// Stage 1: value proj + off/attn proj, heterogeneous persistent launch
// (round-14 base: 256 blocks x 1024 thr, B in VGPRs, A dbuf in LDS,
// 1-deep prefetch, one __syncthreads per tile, swapped-MFMA packed stores).
// NEW: wave owns 32 n-cols (2 breg sets) x 16 m-rows (2 m-groups x 8
// n-groups) -> each wave reads HALF the A-tile from LDS (8 KB vs 16 KB):
// LDS pipe time per tile halves, a-frag ds_read count halves, one m/S
// division per tile.
//   blocks 0..142   : enc @ W_val^T   -> vflat bf16
//   blocks 143..255 : hidden @ [W_off;W_attn]^T -> proj f16 [M][96]
// ---------------------------------------------------------------------------
__global__ __launch_bounds__(1024) void stage1(
    const float* __restrict__ enc, const float* __restrict__ Wval,
    const float* __restrict__ bval, unsigned short* __restrict__ vflat,
    const float* __restrict__ hidden, const float* __restrict__ Woff,
    const float* __restrict__ Wattn, const float* __restrict__ boff,
    const float* __restrict__ battn, unsigned short* __restrict__ proj)
{
    __shared__ __align__(16) short As[2][32 * 256];   // 2 x 16 KB

    const int tid  = threadIdx.x;
    const int lane = tid & 63, w = tid >> 6;
    const int l15  = lane & 15, l4 = lane >> 4;
    const int arow = tid >> 5, ak = (tid & 31) * 8;

    constexpr int NV = 143, NJ = 113;

    if (blockIdx.x < NV) {
        // ---------------- value projection ----------------
        const int mg = w >> 3;            // m-group: rows mg*16..mg*16+15
        const int ng = w & 7;             // n-group: cols ng*32..ng*32+31
        short8 breg[2][8];
#pragma unroll
        for (int j = 0; j < 2; ++j) {
            const int row = ng * 32 + j * 16 + l15;
#pragma unroll
            for (int ks = 0; ks < 8; ++ks) {
                const float* s = &Wval[(size_t)row * K + ks * 32 + l4 * 8];
                breg[j][ks] = cvt8(*reinterpret_cast<const float4*>(s),
                                   *reinterpret_cast<const float4*>(s + 4));
            }
        }
        const int n00 = ng * 32 + l4 * 4;        // j=0 output n-range
        const int n01 = n00 + 16;                // j=1
        const float4 b40 = *reinterpret_cast<const float4*>(&bval[n00]);
        const float4 b41 = *reinterpret_cast<const float4*>(&bval[n01]);
        const int dd00 = n00 & 31, dd01 = n01 & 31;   // h = ng for both

        int t = blockIdx.x;
        float4 fa0, fa1;
        auto lda = [&](int tt) {
            const float* s = &enc[(size_t)(tt * 32 + arow) * K + ak];
            fa0 = *reinterpret_cast<const float4*>(s);
            fa1 = *reinterpret_cast<const float4*>(s + 4);
        };
        lda(t);
        lds_st16s(As[0], arow, 256, ak, cvt8(fa0, fa1));
        __syncthreads();
        int cur = 0;
        for (; t < NTILES; t += NV) {
            const bool more = (t + NV < NTILES);
            if (more) lda(t + NV);            // overlaps MFMA below

            f32x4 acc0 = {0.f, 0.f, 0.f, 0.f}, acc1 = {0.f, 0.f, 0.f, 0.f};
#pragma unroll
            for (int ks = 0; ks < 8; ++ks) {
                const short8 a = lds_ld16s(As[cur], mg * 16 + l15, 256, ks * 32 + l4 * 8);
                acc0 = __builtin_amdgcn_mfma_f32_16x16x32_bf16(breg[0][ks], a, acc0, 0, 0, 0);
                acc1 = __builtin_amdgcn_mfma_f32_16x16x32_bf16(breg[1][ks], a, acc1, 0, 0, 0);
            }
            const int m = t * 32 + mg * 16 + l15;
            const int b_ = m / S, s_ = m - b_ * S;
            const size_t obase = (((size_t)(b_ * NH + ng)) * S + s_) * DH;
            {
                ushort4p pk;
                pk.x = f2bf(acc0[0] + b40.x);
                pk.y = f2bf(acc0[1] + b40.y);
                pk.z = f2bf(acc0[2] + b40.z);
                pk.w = f2bf(acc0[3] + b40.w);
                *reinterpret_cast<ushort4p*>(&vflat[obase + dd00]) = pk;
            }
            {
                ushort4p pk;
                pk.x = f2bf(acc1[0] + b41.x);
                pk.y = f2bf(acc1[1] + b41.y);
                pk.z = f2bf(acc1[2] + b41.z);
                pk.w = f2bf(acc1[3] + b41.w);
                *reinterpret_cast<ushort4p*>(&vflat[obase + dd01]) = pk;
            }
            if (more) lds_st16s(As[cur ^ 1], arow, 256, ak, cvt8(fa0, fa1));
            __syncthreads();
            cur ^= 1;
        }
    } else {
        // ---------------- off+attn projection ----------------
        // waves 0..5 compute: ng = w>>1 (0..2, 32 cols each), mg = w&1.
        const int ng = w >> 1, mg = w & 1;
        short8 breg[2][8];
        float4 b40 = {0.f, 0.f, 0.f, 0.f}, b41 = {0.f, 0.f, 0.f, 0.f};
        int n00 = 0, n01 = 0;
        if (w < 6) {
#pragma unroll
            for (int j = 0; j < 2; ++j) {
                const int row = ng * 32 + j * 16 + l15;
#pragma unroll
                for (int ks = 0; ks < 8; ++ks) {
                    const float* s = (row < 64)
                        ? &Woff[(size_t)row * K + ks * 32 + l4 * 8]
                        : &Wattn[(size_t)(row - 64) * K + ks * 32 + l4 * 8];
                    breg[j][ks] = cvt8(*reinterpret_cast<const float4*>(s),
                                       *reinterpret_cast<const float4*>(s + 4));
                }
            }
            n00 = ng * 32 + l4 * 4;
            n01 = n00 + 16;
            b40 = (n00 < 64) ? *reinterpret_cast<const float4*>(&boff[n00])
                             : *reinterpret_cast<const float4*>(&battn[n00 - 64]);
            b41 = (n01 < 64) ? *reinterpret_cast<const float4*>(&boff[n01])
                             : *reinterpret_cast<const float4*>(&battn[n01 - 64]);
        }

        int t = blockIdx.x - NV;
        float4 fa0, fa1;
        auto lda = [&](int tt) {
            const float* s = &hidden[(size_t)(tt * 32 + arow) * K + ak];
            fa0 = *reinterpret_cast<const float4*>(s);
            fa1 = *reinterpret_cast<const float4*>(s + 4);
        };
        lda(t);
        lds_st16s(As[0], arow, 256, ak, cvt8(fa0, fa1));
        __syncthreads();
        int cur = 0;
        for (; t < NTILES; t += NJ) {
            const bool more = (t + NJ < NTILES);
            if (more) lda(t + NJ);

            if (w < 6) {
                f32x4 acc0 = {0.f, 0.f, 0.f, 0.f}, acc1 = {0.f, 0.f, 0.f, 0.f};
#pragma unroll
                for (int ks = 0; ks < 8; ++ks) {
                    const short8 a = lds_ld16s(As[cur], mg * 16 + l15, 256, ks * 32 + l4 * 8);
                    acc0 = __builtin_amdgcn_mfma_f32_16x16x32_bf16(breg[0][ks], a, acc0, 0, 0, 0);
                    acc1 = __builtin_amdgcn_mfma_f32_16x16x32_bf16(breg[1][ks], a, acc1, 0, 0, 0);
                }
                const int m = t * 32 + mg * 16 + l15;
                {
                    ushort4p pk;
                    pk.x = f2h(acc0[0] + b40.x);
                    pk.y = f2h(acc0[1] + b40.y);
                    pk.z = f2h(acc0[2] + b40.z);
                    pk.w = f2h(acc0[3] + b40.w);
                    *reinterpret_cast<ushort4p*>(&proj[(size_t)m * 96 + n00]) = pk;
                }
                {
                    ushort4p pk;
                    pk.x = f2h(acc1[0] + b41.x);
                    pk.y = f2h(acc1[1] + b41.y);
                    pk.z = f2h(acc1[2] + b41.z);
                    pk.w = f2h(acc1[3] + b41.w);
                    *reinterpret_cast<ushort4p*>(&proj[(size_t)m * 96 + n01]) = pk;
                }
            }
            if (more) lds_st16s(As[cur ^ 1], arow, 256, ak, cvt8(fa0, fa1));
            __syncthreads();
            cur ^= 1;
        }
    }
}

// ---------------------------------------------------------------------------
// Kernel S: bilinear sampling + attention aggregation (round-10/14 version).
// 4 lanes per (b,h,q) group; lane owns 8 d-elements (16B gathers).
// 64 groups per 256-thread block; 5000 blocks, XCD-swizzled.
// ---------------------------------------------------------------------------
__global__ __launch_bounds__(256) void sample_agg(
    const unsigned short* __restrict__ vflat,  // [B*NH][S][DH] bf16
    const unsigned short* __restrict__ proj,   // [M][96] f16
    const float* __restrict__ ref,             // [M][2]
    unsigned short* __restrict__ tmp)          // [M][256] bf16
{
    const int nblk = gridDim.x;                // 5000, %8 == 0
    const int cpx  = nblk >> 3;
    const int swz  = (blockIdx.x & 7) * cpx + (blockIdx.x >> 3);

    const int lg   = threadIdx.x >> 2;   // 0..63
    const int lane = threadIdx.x & 3;
    const int d0   = lane * 8;

    const int g  = swz * 64 + lg;
    const int q  = g % Q;
    const int bh = g / Q;
    const int b  = bh >> 3;
    const int h  = bh & 7;

    const size_t bq = (size_t)b * Q + q;
    const float refx = ref[bq * 2 + 0];
    const float refy = ref[bq * 2 + 1];
    const unsigned short* pr = proj + bq * 96;

    float l[NP];
#pragma unroll
    for (int p = 0; p < NP; ++p) l[p] = h2f(pr[64 + h * 4 + p]);
    const float mx = fmaxf(fmaxf(l[0], l[1]), fmaxf(l[2], l[3]));
    float e[NP];
    float esum = 0.f;
#pragma unroll
    for (int p = 0; p < NP; ++p) { e[p] = __expf(l[p] - mx); esum += e[p]; }
    const float inv = 1.f / esum;

    const unsigned short* vbase = vflat + (size_t)bh * (S * DH);

    int   cidx[NP][4];
    float cw[NP][4];
#pragma unroll
    for (int p = 0; p < NP; ++p) {
        const float ox = h2f(pr[h * 8 + p * 2 + 0]);
        const float oy = h2f(pr[h * 8 + p * 2 + 1]);
        const float x = fmaf(refx, (float)WW, ox) - 0.5f;
        const float y = fmaf(refy, (float)HH, oy) - 0.5f;
        const float x0f = floorf(x), y0f = floorf(y);
        const float wx1 = x - x0f, wx0 = 1.f - wx1;
        const float wy1 = y - y0f, wy0 = 1.f - wy1;
        const int x0 = (int)x0f, y0 = (int)y0f;
        const bool vx0 = (x0 >= 0) && (x0 < WW);
        const bool vx1 = (x0 + 1 >= 0) && (x0 + 1 < WW);
        const bool vy0 = (y0 >= 0) && (y0 < HH);
        const bool vy1 = (y0 + 1 >= 0) && (y0 + 1 < HH);
        const int xi0 = min(max(x0, 0), WW - 1);
        const int xi1 = min(max(x0 + 1, 0), WW - 1);
        const int yi0 = min(max(y0, 0), HH - 1);
        const int yi1 = min(max(y0 + 1, 0), HH - 1);
        const float ap = e[p] * inv;
        cw[p][0] = ap * wx0 * wy0 * ((vx0 && vy0) ? 1.f : 0.f);
        cw[p][1] = ap * wx1 * wy0 * ((vx1 && vy0) ? 1.f : 0.f);
        cw[p][2] = ap * wx0 * wy1 * ((vx0 && vy1) ? 1.f : 0.f);
        cw[p][3] = ap * wx1 * wy1 * ((vx1 && vy1) ? 1.f : 0.f);
        cidx[p][0] = (yi0 * WW + xi0) * DH + d0;
        cidx[p][1] = (yi0 * WW + xi1) * DH + d0;
        cidx[p][2] = (yi1 * WW + xi0) * DH + d0;
        cidx[p][3] = (yi1 * WW + xi1) * DH + d0;
    }

    float o[8];
#pragma unroll
    for (int j = 0; j < 8; ++j) o[j] = 0.f;
#pragma unroll
    for (int p = 0; p < NP; ++p) {
#pragma unroll
        for (int c = 0; c < 4; ++c) {
            const short8 v = *reinterpret_cast<const short8*>(&vbase[cidx[p][c]]);
            const float wgt = cw[p][c];
#pragma unroll
            for (int j = 0; j < 8; ++j)
                o[j] = fmaf(wgt, bf2f((unsigned short)v[j]), o[j]);
        }
    }

    short8 ov;
#pragma unroll
    for (int j = 0; j < 8; ++j) ov[j] = (short)f2bf(o[j]);
    *reinterpret_cast<short8*>(&tmp[bq * 256 + h * 32 + d0]) = ov;
}

// ---------------------------------------------------------------------------
// Kernel O: out projection (round-14 base). NEW: wave owns 32 n-cols x 16
// m-rows (2 breg sets) -> half the LDS A-reads per wave.
// ---------------------------------------------------------------------------
__global__ __launch_bounds__(1024) void out_proj(
    const unsigned short* __restrict__ tmp, const float* __restrict__ Wo,
    const float* __restrict__ bo, float* __restrict__ out)
{
    __shared__ __align__(16) short As[2][32 * 256];   // 2 x 16 KB

    const int tid  = threadIdx.x;
    const int lane = tid & 63, w = tid >> 6;
    const int l15  = lane & 15, l4 = lane >> 4;
    const int arow = tid >> 5, ak = (tid & 31) * 8;

    const int mg = w >> 3;            // rows mg*16..mg*16+15
    const int ng = w & 7;             // cols ng*32..ng*32+31
    short8 breg[2][8];
#pragma unroll
    for (int j = 0; j < 2; ++j) {
        const int row = ng * 32 + j * 16 + l15;
#pragma unroll
        for (int ks = 0; ks < 8; ++ks) {
            const float* s = &Wo[(size_t)row * K + ks * 32 + l4 * 8];
            breg[j][ks] = cvt8(*reinterpret_cast<const float4*>(s),
                               *reinterpret_cast<const float4*>(s + 4));
        }
    }
    const int n00 = ng * 32 + l4 * 4;
    const int n01 = n00 + 16;
    const float4 b40 = *reinterpret_cast<const float4*>(&bo[n00]);
    const float4 b41 = *reinterpret_cast<const float4*>(&bo[n01]);

    int t = blockIdx.x;
    short8 sa;
    auto lda = [&](int tt) {
        sa = *reinterpret_cast<const short8*>(&tmp[(size_t)(tt * 32 + arow) * K + ak]);
    };
    lda(t);
    lds_st16s(As[0], arow, 256, ak, sa);
    __syncthreads();
    int cur = 0;
    for (; t < NTILES; t += 256) {
        const bool more = (t + 256 < NTILES);
        if (more) lda(t + 256);

        f32x4 acc0 = {0.f, 0.f, 0.f, 0.f}, acc1 = {0.f, 0.f, 0.f, 0.f};
#pragma unroll
        for (int ks = 0; ks < 8; ++ks) {
            const short8 a = lds_ld16s(As[cur], mg * 16 + l15, 256, ks * 32 + l4 * 8);
            acc0 = __builtin_amdgcn_mfma_f32_16x16x32_bf16(breg[0][ks], a, acc0, 0, 0, 0);
            acc1 = __builtin_amdgcn_mfma_f32_16x16x32_bf16(breg[1][ks], a, acc1, 0, 0, 0);
        }
        const int m = t * 32 + mg * 16 + l15;
        {
            float4 pv;
            pv.x = acc0[0] + b40.x; pv.y = acc0[1] + b40.y;
            pv.z = acc0[2] + b40.z; pv.w = acc0[3] + b40.w;
            *reinterpret_cast<float4*>(&out[(size_t)m * K + n00]) = pv;
        }
        {
            float4 pv;
            pv.x = acc1[0] + b41.x; pv.y = acc1[1] + b41.y;
            pv.z = acc1[2] + b41.z; pv.w = acc1[3] + b41.w;
            *reinterpret_cast<float4*>(&out[(size_t)m * K + n01]) = pv;
        }
        if (more) lds_st16s(As[cur ^ 1], arow, 256, ak, sa);
        __syncthreads();
        cur ^= 1;
    }
}

// ---------------------------------------------------------------------------
extern "C" void kernel_launch(void* const* d_in, const int* in_sizes, int n_in,
                              void* d_out, int out_size, void* d_ws, size_t ws_size,
                              hipStream_t stream)
{
    const float* hidden = (const float*)d_in[0];
    const float* enc    = (const float*)d_in[1];
    const float* refp   = (const float*)d_in[2];
    const float* W_off  = (const float*)d_in[4];
    const float* b_off  = (const float*)d_in[5];
    const float* W_attn = (const float*)d_in[6];
    const float* b_attn = (const float*)d_in[7];
    const float* W_val  = (const float*)d_in[8];
    const float* b_val  = (const float*)d_in[9];
    const float* W_out  = (const float*)d_in[10];
    const float* b_out  = (const float*)d_in[11];
    float* out = (float*)d_out;

    // workspace (u16 elements): vflat | proj | tmp
    unsigned short* vflat = (unsigned short*)d_ws;     // 10,240,000
    unsigned short* proj  = vflat + (size_t)10240000;  //  3,840,000
    unsigned short* tmp   = proj + (size_t)3840000;    // 10,240,000

    // 1) value proj (143 blocks) + off/attn proj (113 blocks), reg-B persistent
    stage1<<<256, 1024, 0, stream>>>(
        enc, W_val, b_val, vflat, hidden, W_off, W_attn, b_off, b_attn, proj);

    // 2) bilinear sampling + softmax aggregation -> tmp bf16 [M][256]
    sample_agg<<<5000, 256, 0, stream>>>(vflat, proj, refp, tmp);

    // 3) out projection (reg-B persistent, A dbuf, packed f32x4 stores) -> f32
    out_proj<<<256, 1024, 0, stream>>>(tmp, W_out, b_out, out);
}

// Round 18
// 89.572 us; speedup vs baseline: 1.5016x; 1.0341x over previous
//
#include <hip/hip_runtime.h>

constexpr int HH = 100;
constexpr int WW = 100;
constexpr int NH = 8;
constexpr int NP = 4;
constexpr int B  = 4;
constexpr int Q  = HH * WW;   // 10000
constexpr int S  = Q;
constexpr int K  = 256;
constexpr int DH = 32;
constexpr int M  = B * Q;     // 40000
constexpr int NTILES = M / 32; // 1250

typedef __attribute__((ext_vector_type(8))) short short8;
typedef __attribute__((ext_vector_type(4))) float f32x4;

struct __align__(8) ushort4p { unsigned short x, y, z, w; };

__device__ inline unsigned short f2bf(float f) {
    unsigned u = __builtin_bit_cast(unsigned, f);
    u += 0x7fffu + ((u >> 16) & 1u);          // RNE
    return (unsigned short)(u >> 16);
}
__device__ inline float bf2f(unsigned short h) {
    return __builtin_bit_cast(float, ((unsigned)h) << 16);
}
__device__ inline unsigned short f2h(float f) {
    _Float16 h = (_Float16)f;
    return __builtin_bit_cast(unsigned short, h);
}
__device__ inline float h2f(unsigned short u) {
    return (float)__builtin_bit_cast(_Float16, u);
}

// LDS bf16 tile helpers (16B-chunk XOR swizzle: chunk ^= row&7).
__device__ inline void lds_st16s(short* base, int row, int stride, int kcol, short8 v) {
    *reinterpret_cast<short8*>(&base[row * stride + (kcol ^ ((row & 7) << 3))]) = v;
}
__device__ inline short8 lds_ld16s(const short* base, int row, int stride, int kcol) {
    return *reinterpret_cast<const short8*>(&base[row * stride + (kcol ^ ((row & 7) << 3))]);
}

__device__ inline short8 cvt8(float4 a, float4 b) {
    short8 r;
    r[0] = (short)f2bf(a.x); r[1] = (short)f2bf(a.y);
    r[2] = (short)f2bf(a.z); r[3] = (short)f2bf(a.w);
    r[4] = (short)f2bf(b.x); r[5] = (short)f2bf(b.y);
    r[6] = (short)f2bf(b.z); r[7] = (short)f2bf(b.w);
    return r;
}

// ---------------------------------------------------------------------------
// Stage 1: value proj + off/attn proj, heterogeneous persistent launch.
// NEW GEOMETRY: 512 blocks x 512 thr (8 waves), __launch_bounds__(512,4)
// caps VGPR at 128 -> TWO resident blocks per CU = two independent barrier
// domains (m114 overlap: one block computes while the other drains).
// Wave owns 32 n-cols (breg[2], 8x32 = 256, weights read ONCE per block)
// and all 32 m-rows (acc[2][2], 4 MFMA/ks). A dbuf in LDS (2 x 16 KB),
// 1-deep prefetch, one __syncthreads per tile, swapped-MFMA packed stores.
//   blocks 0..285   : enc @ W_val^T   -> vflat bf16
//   blocks 286..511 : hidden @ [W_off;W_attn]^T -> proj f16 [M][96]
// ---------------------------------------------------------------------------
__global__ __launch_bounds__(512, 4) void stage1(
    const float* __restrict__ enc, const float* __restrict__ Wval,
    const float* __restrict__ bval, unsigned short* __restrict__ vflat,
    const float* __restrict__ hidden, const float* __restrict__ Woff,
    const float* __restrict__ Wattn, const float* __restrict__ boff,
    const float* __restrict__ battn, unsigned short* __restrict__ proj)
{
    __shared__ __align__(16) short As[2][32 * 256];   // 2 x 16 KB

    const int tid  = threadIdx.x;
    const int lane = tid & 63, w = tid >> 6;          // 8 waves
    const int l15  = lane & 15, l4 = lane >> 4;
    // staging: 2 units per thread (R14 mapping), unit u -> row u>>5, chunk (u&31)*8
    const int ar0 = tid >> 5;            // 0..15
    const int ar1 = 16 + ar0;            // 16..31
    const int ak  = (tid & 31) * 8;

    constexpr int NV = 286, NJ = 226;

    if (blockIdx.x < NV) {
        // ---------------- value projection ----------------
        short8 breg[2][8];
#pragma unroll
        for (int j = 0; j < 2; ++j) {
            const int row = w * 32 + j * 16 + l15;
#pragma unroll
            for (int ks = 0; ks < 8; ++ks) {
                const float* s = &Wval[(size_t)row * K + ks * 32 + l4 * 8];
                breg[j][ks] = cvt8(*reinterpret_cast<const float4*>(s),
                                   *reinterpret_cast<const float4*>(s + 4));
            }
        }
        const int n00 = w * 32 + l4 * 4;          // j=0 output cols
        const int n01 = n00 + 16;                 // j=1
        const float4 b40 = *reinterpret_cast<const float4*>(&bval[n00]);
        const float4 b41 = *reinterpret_cast<const float4*>(&bval[n01]);
        const int dd0 = n00 & 31, dd1 = n01 & 31; // h = w for both

        int t = blockIdx.x;
        float4 f00, f01, f10, f11;
        auto lda = [&](int tt) {
            const float* s0 = &enc[(size_t)(tt * 32 + ar0) * K + ak];
            f00 = *reinterpret_cast<const float4*>(s0);
            f01 = *reinterpret_cast<const float4*>(s0 + 4);
            const float* s1 = &enc[(size_t)(tt * 32 + ar1) * K + ak];
            f10 = *reinterpret_cast<const float4*>(s1);
            f11 = *reinterpret_cast<const float4*>(s1 + 4);
        };
        auto wr = [&](short* dst) {
            lds_st16s(dst, ar0, 256, ak, cvt8(f00, f01));
            lds_st16s(dst, ar1, 256, ak, cvt8(f10, f11));
        };
        lda(t);
        wr(As[0]);
        __syncthreads();
        int cur = 0;
        for (; t < NTILES; t += NV) {
            const bool more = (t + NV < NTILES);
            if (more) lda(t + NV);            // overlaps MFMA below

            f32x4 acc[2][2];
#pragma unroll
            for (int i = 0; i < 2; ++i)
#pragma unroll
                for (int j = 0; j < 2; ++j) acc[i][j] = f32x4{0.f, 0.f, 0.f, 0.f};
#pragma unroll
            for (int ks = 0; ks < 8; ++ks) {
                const int kc = ks * 32 + l4 * 8;
                const short8 a0 = lds_ld16s(As[cur], l15, 256, kc);
                const short8 a1 = lds_ld16s(As[cur], 16 + l15, 256, kc);
                acc[0][0] = __builtin_amdgcn_mfma_f32_16x16x32_bf16(breg[0][ks], a0, acc[0][0], 0, 0, 0);
                acc[0][1] = __builtin_amdgcn_mfma_f32_16x16x32_bf16(breg[1][ks], a0, acc[0][1], 0, 0, 0);
                acc[1][0] = __builtin_amdgcn_mfma_f32_16x16x32_bf16(breg[0][ks], a1, acc[1][0], 0, 0, 0);
                acc[1][1] = __builtin_amdgcn_mfma_f32_16x16x32_bf16(breg[1][ks], a1, acc[1][1], 0, 0, 0);
            }
#pragma unroll
            for (int mf = 0; mf < 2; ++mf) {
                const int m = t * 32 + mf * 16 + l15;
                const int b_ = m / S, s_ = m - b_ * S;
                const size_t obase = (((size_t)(b_ * NH + w)) * S + s_) * DH;
                ushort4p p0;
                p0.x = f2bf(acc[mf][0][0] + b40.x);
                p0.y = f2bf(acc[mf][0][1] + b40.y);
                p0.z = f2bf(acc[mf][0][2] + b40.z);
                p0.w = f2bf(acc[mf][0][3] + b40.w);
                *reinterpret_cast<ushort4p*>(&vflat[obase + dd0]) = p0;
                ushort4p p1;
                p1.x = f2bf(acc[mf][1][0] + b41.x);
                p1.y = f2bf(acc[mf][1][1] + b41.y);
                p1.z = f2bf(acc[mf][1][2] + b41.z);
                p1.w = f2bf(acc[mf][1][3] + b41.w);
                *reinterpret_cast<ushort4p*>(&vflat[obase + dd1]) = p1;
            }
            if (more) wr(As[cur ^ 1]);
            __syncthreads();
            cur ^= 1;
        }
    } else {
        // ---------------- off+attn projection ----------------
        // waves 0..5 compute 16 cols each (6 x 16 = 96); waves 6,7 stage only.
        short8 breg[8];
        float4 bias4 = {0.f, 0.f, 0.f, 0.f};
        const int n0 = w * 16 + l4 * 4;
        if (w < 6) {
            const int row = w * 16 + l15;
#pragma unroll
            for (int ks = 0; ks < 8; ++ks) {
                const float* s = (row < 64)
                    ? &Woff[(size_t)row * K + ks * 32 + l4 * 8]
                    : &Wattn[(size_t)(row - 64) * K + ks * 32 + l4 * 8];
                breg[ks] = cvt8(*reinterpret_cast<const float4*>(s),
                                *reinterpret_cast<const float4*>(s + 4));
            }
            bias4 = (n0 < 64)
                ? *reinterpret_cast<const float4*>(&boff[n0])
                : *reinterpret_cast<const float4*>(&battn[n0 - 64]);
        }

        int t = blockIdx.x - NV;
        float4 f00, f01, f10, f11;
        auto lda = [&](int tt) {
            const float* s0 = &hidden[(size_t)(tt * 32 + ar0) * K + ak];
            f00 = *reinterpret_cast<const float4*>(s0);
            f01 = *reinterpret_cast<const float4*>(s0 + 4);
            const float* s1 = &hidden[(size_t)(tt * 32 + ar1) * K + ak];
            f10 = *reinterpret_cast<const float4*>(s1);
            f11 = *reinterpret_cast<const float4*>(s1 + 4);
        };
        auto wr = [&](short* dst) {
            lds_st16s(dst, ar0, 256, ak, cvt8(f00, f01));
            lds_st16s(dst, ar1, 256, ak, cvt8(f10, f11));
        };
        lda(t);
        wr(As[0]);
        __syncthreads();
        int cur = 0;
        for (; t < NTILES; t += NJ) {
            const bool more = (t + NJ < NTILES);
            if (more) lda(t + NJ);

            if (w < 6) {
                f32x4 acc0 = {0.f, 0.f, 0.f, 0.f}, acc1 = {0.f, 0.f, 0.f, 0.f};
#pragma unroll
                for (int ks = 0; ks < 8; ++ks) {
                    const int kc = ks * 32 + l4 * 8;
                    const short8 a0 = lds_ld16s(As[cur], l15, 256, kc);
                    const short8 a1 = lds_ld16s(As[cur], 16 + l15, 256, kc);
                    acc0 = __builtin_amdgcn_mfma_f32_16x16x32_bf16(breg[ks], a0, acc0, 0, 0, 0);
                    acc1 = __builtin_amdgcn_mfma_f32_16x16x32_bf16(breg[ks], a1, acc1, 0, 0, 0);
                }
                {
                    const int m = t * 32 + l15;
                    ushort4p pk;
                    pk.x = f2h(acc0[0] + bias4.x);
                    pk.y = f2h(acc0[1] + bias4.y);
                    pk.z = f2h(acc0[2] + bias4.z);
                    pk.w = f2h(acc0[3] + bias4.w);
                    *reinterpret_cast<ushort4p*>(&proj[(size_t)m * 96 + n0]) = pk;
                }
                {
                    const int m = t * 32 + 16 + l15;
                    ushort4p pk;
                    pk.x = f2h(acc1[0] + bias4.x);
                    pk.y = f2h(acc1[1] + bias4.y);
                    pk.z = f2h(acc1[2] + bias4.z);
                    pk.w = f2h(acc1[3] + bias4.w);
                    *reinterpret_cast<ushort4p*>(&proj[(size_t)m * 96 + n0]) = pk;
                }
            }
            if (more) wr(As[cur ^ 1]);
            __syncthreads();
            cur ^= 1;
        }
    }
}

// ---------------------------------------------------------------------------
// Kernel S: bilinear sampling + attention aggregation (round-10/14 version).
// 4 lanes per (b,h,q) group; lane owns 8 d-elements (16B gathers).
// 64 groups per 256-thread block; 5000 blocks, XCD-swizzled.
// ---------------------------------------------------------------------------
__global__ __launch_bounds__(256) void sample_agg(
    const unsigned short* __restrict__ vflat,  // [B*NH][S][DH] bf16
    const unsigned short* __restrict__ proj,   // [M][96] f16
    const float* __restrict__ ref,             // [M][2]
    unsigned short* __restrict__ tmp)          // [M][256] bf16
{
    const int nblk = gridDim.x;                // 5000, %8 == 0
    const int cpx  = nblk >> 3;
    const int swz  = (blockIdx.x & 7) * cpx + (blockIdx.x >> 3);

    const int lg   = threadIdx.x >> 2;   // 0..63
    const int lane = threadIdx.x & 3;
    const int d0   = lane * 8;

    const int g  = swz * 64 + lg;
    const int q  = g % Q;
    const int bh = g / Q;
    const int b  = bh >> 3;
    const int h  = bh & 7;

    const size_t bq = (size_t)b * Q + q;
    const float refx = ref[bq * 2 + 0];
    const float refy = ref[bq * 2 + 1];
    const unsigned short* pr = proj + bq * 96;

    float l[NP];
#pragma unroll
    for (int p = 0; p < NP; ++p) l[p] = h2f(pr[64 + h * 4 + p]);
    const float mx = fmaxf(fmaxf(l[0], l[1]), fmaxf(l[2], l[3]));
    float e[NP];
    float esum = 0.f;
#pragma unroll
    for (int p = 0; p < NP; ++p) { e[p] = __expf(l[p] - mx); esum += e[p]; }
    const float inv = 1.f / esum;

    const unsigned short* vbase = vflat + (size_t)bh * (S * DH);

    int   cidx[NP][4];
    float cw[NP][4];
#pragma unroll
    for (int p = 0; p < NP; ++p) {
        const float ox = h2f(pr[h * 8 + p * 2 + 0]);
        const float oy = h2f(pr[h * 8 + p * 2 + 1]);
        const float x = fmaf(refx, (float)WW, ox) - 0.5f;
        const float y = fmaf(refy, (float)HH, oy) - 0.5f;
        const float x0f = floorf(x), y0f = floorf(y);
        const float wx1 = x - x0f, wx0 = 1.f - wx1;
        const float wy1 = y - y0f, wy0 = 1.f - wy1;
        const int x0 = (int)x0f, y0 = (int)y0f;
        const bool vx0 = (x0 >= 0) && (x0 < WW);
        const bool vx1 = (x0 + 1 >= 0) && (x0 + 1 < WW);
        const bool vy0 = (y0 >= 0) && (y0 < HH);
        const bool vy1 = (y0 + 1 >= 0) && (y0 + 1 < HH);
        const int xi0 = min(max(x0, 0), WW - 1);
        const int xi1 = min(max(x0 + 1, 0), WW - 1);
        const int yi0 = min(max(y0, 0), HH - 1);
        const int yi1 = min(max(y0 + 1, 0), HH - 1);
        const float ap = e[p] * inv;
        cw[p][0] = ap * wx0 * wy0 * ((vx0 && vy0) ? 1.f : 0.f);
        cw[p][1] = ap * wx1 * wy0 * ((vx1 && vy0) ? 1.f : 0.f);
        cw[p][2] = ap * wx0 * wy1 * ((vx0 && vy1) ? 1.f : 0.f);
        cw[p][3] = ap * wx1 * wy1 * ((vx1 && vy1) ? 1.f : 0.f);
        cidx[p][0] = (yi0 * WW + xi0) * DH + d0;
        cidx[p][1] = (yi0 * WW + xi1) * DH + d0;
        cidx[p][2] = (yi1 * WW + xi0) * DH + d0;
        cidx[p][3] = (yi1 * WW + xi1) * DH + d0;
    }

    float o[8];
#pragma unroll
    for (int j = 0; j < 8; ++j) o[j] = 0.f;
#pragma unroll
    for (int p = 0; p < NP; ++p) {
#pragma unroll
        for (int c = 0; c < 4; ++c) {
            const short8 v = *reinterpret_cast<const short8*>(&vbase[cidx[p][c]]);
            const float wgt = cw[p][c];
#pragma unroll
            for (int j = 0; j < 8; ++j)
                o[j] = fmaf(wgt, bf2f((unsigned short)v[j]), o[j]);
        }
    }

    short8 ov;
#pragma unroll
    for (int j = 0; j < 8; ++j) ov[j] = (short)f2bf(o[j]);
    *reinterpret_cast<short8*>(&tmp[bq * 256 + h * 32 + d0]) = ov;
}

// ---------------------------------------------------------------------------
// Kernel O: out projection (round-14 version: 256 blocks x 1024 thr,
// W in VGPRs, A dbuf in LDS, 1-deep prefetch, __syncthreads per tile,
// swapped-MFMA packed f32x4 stores).
// ---------------------------------------------------------------------------
__global__ __launch_bounds__(1024) void out_proj(
    const unsigned short* __restrict__ tmp, const float* __restrict__ Wo,
    const float* __restrict__ bo, float* __restrict__ out)
{
    __shared__ __align__(16) short As[2][32 * 256];   // 2 x 16 KB

    const int tid  = threadIdx.x;
    const int lane = tid & 63, w = tid >> 6;
    const int l15  = lane & 15, l4 = lane >> 4;
    const int arow = tid >> 5, ak = (tid & 31) * 8;

    const int n = w * 16 + l15;               // lane's weight row
    short8 breg[8];
#pragma unroll
    for (int ks = 0; ks < 8; ++ks) {
        const float* s = &Wo[(size_t)n * K + ks * 32 + l4 * 8];
        breg[ks] = cvt8(*reinterpret_cast<const float4*>(s),
                        *reinterpret_cast<const float4*>(s + 4));
    }
    const int nbase = w * 16 + l4 * 4;        // output n-range after swap
    const float4 bias4 = *reinterpret_cast<const float4*>(&bo[nbase]);

    int t = blockIdx.x;
    short8 sa;
    auto lda = [&](int tt) {
        sa = *reinterpret_cast<const short8*>(&tmp[(size_t)(tt * 32 + arow) * K + ak]);
    };
    lda(t);
    lds_st16s(As[0], arow, 256, ak, sa);
    __syncthreads();
    int cur = 0;
    for (; t < NTILES; t += 256) {
        const bool more = (t + 256 < NTILES);
        if (more) lda(t + 256);

        f32x4 acc0 = {0.f, 0.f, 0.f, 0.f}, acc1 = {0.f, 0.f, 0.f, 0.f};
#pragma unroll
        for (int ks = 0; ks < 8; ++ks) {
            const int kc = ks * 32 + l4 * 8;
            const short8 a0 = lds_ld16s(As[cur], l15, 256, kc);
            const short8 a1 = lds_ld16s(As[cur], 16 + l15, 256, kc);
            acc0 = __builtin_amdgcn_mfma_f32_16x16x32_bf16(breg[ks], a0, acc0, 0, 0, 0);
            acc1 = __builtin_amdgcn_mfma_f32_16x16x32_bf16(breg[ks], a1, acc1, 0, 0, 0);
        }
        const int m0 = t * 32;
        {
            const int m = m0 + l15;
            float4 pv;
            pv.x = acc0[0] + bias4.x; pv.y = acc0[1] + bias4.y;
            pv.z = acc0[2] + bias4.z; pv.w = acc0[3] + bias4.w;
            *reinterpret_cast<float4*>(&out[(size_t)m * K + nbase]) = pv;
        }
        {
            const int m = m0 + 16 + l15;
            float4 pv;
            pv.x = acc1[0] + bias4.x; pv.y = acc1[1] + bias4.y;
            pv.z = acc1[2] + bias4.z; pv.w = acc1[3] + bias4.w;
            *reinterpret_cast<float4*>(&out[(size_t)m * K + nbase]) = pv;
        }
        if (more) lds_st16s(As[cur ^ 1], arow, 256, ak, sa);
        __syncthreads();
        cur ^= 1;
    }
}

// ---------------------------------------------------------------------------
extern "C" void kernel_launch(void* const* d_in, const int* in_sizes, int n_in,
                              void* d_out, int out_size, void* d_ws, size_t ws_size,
                              hipStream_t stream)
{
    const float* hidden = (const float*)d_in[0];
    const float* enc    = (const float*)d_in[1];
    const float* refp   = (const float*)d_in[2];
    const float* W_off  = (const float*)d_in[4];
    const float* b_off  = (const float*)d_in[5];
    const float* W_attn = (const float*)d_in[6];
    const float* b_attn = (const float*)d_in[7];
    const float* W_val  = (const float*)d_in[8];
    const float* b_val  = (const float*)d_in[9];
    const float* W_out  = (const float*)d_in[10];
    const float* b_out  = (const float*)d_in[11];
    float* out = (float*)d_out;

    // workspace (u16 elements): vflat | proj | tmp
    unsigned short* vflat = (unsigned short*)d_ws;     // 10,240,000
    unsigned short* proj  = vflat + (size_t)10240000;  //  3,840,000
    unsigned short* tmp   = proj + (size_t)3840000;    // 10,240,000

    // 1) value proj (286 blocks) + off/attn proj (226 blocks),
    //    512-thr blocks -> 2 barrier domains per CU
    stage1<<<512, 512, 0, stream>>>(
        enc, W_val, b_val, vflat, hidden, W_off, W_attn, b_off, b_attn, proj);

    // 2) bilinear sampling + softmax aggregation -> tmp bf16 [M][256]
    sample_agg<<<5000, 256, 0, stream>>>(vflat, proj, refp, tmp);

    // 3) out projection (reg-B persistent, A dbuf, packed f32x4 stores) -> f32
    out_proj<<<256, 1024, 0, stream>>>(tmp, W_out, b_out, out);
}

// Round 19
// 73.396 us; speedup vs baseline: 1.8325x; 1.2204x over previous
//
#include <hip/hip_runtime.h>

constexpr int HH = 100;
constexpr int WW = 100;
constexpr int NH = 8;
constexpr int NP = 4;
constexpr int B  = 4;
constexpr int Q  = HH * WW;   // 10000
constexpr int S  = Q;
constexpr int K  = 256;
constexpr int DH = 32;
constexpr int M  = B * Q;     // 40000
constexpr int NTILES = M / 32; // 1250

typedef __attribute__((ext_vector_type(8))) short short8;
typedef __attribute__((ext_vector_type(4))) float f32x4;

struct __align__(8) ushort4p { unsigned short x, y, z, w; };

__device__ inline unsigned short f2bf(float f) {
    unsigned u = __builtin_bit_cast(unsigned, f);
    u += 0x7fffu + ((u >> 16) & 1u);          // RNE
    return (unsigned short)(u >> 16);
}
__device__ inline float bf2f(unsigned short h) {
    return __builtin_bit_cast(float, ((unsigned)h) << 16);
}
__device__ inline unsigned short f2h(float f) {
    _Float16 h = (_Float16)f;
    return __builtin_bit_cast(unsigned short, h);
}
__device__ inline float h2f(unsigned short u) {
    return (float)__builtin_bit_cast(_Float16, u);
}

// LDS bf16 tile helpers (16B-chunk XOR swizzle: chunk ^= row&7).
__device__ inline void lds_st16s(short* base, int row, int stride, int kcol, short8 v) {
    *reinterpret_cast<short8*>(&base[row * stride + (kcol ^ ((row & 7) << 3))]) = v;
}
__device__ inline short8 lds_ld16s(const short* base, int row, int stride, int kcol) {
    return *reinterpret_cast<const short8*>(&base[row * stride + (kcol ^ ((row & 7) << 3))]);
}

__device__ inline short8 cvt8(float4 a, float4 b) {
    short8 r;
    r[0] = (short)f2bf(a.x); r[1] = (short)f2bf(a.y);
    r[2] = (short)f2bf(a.z); r[3] = (short)f2bf(a.w);
    r[4] = (short)f2bf(b.x); r[5] = (short)f2bf(b.y);
    r[6] = (short)f2bf(b.z); r[7] = (short)f2bf(b.w);
    return r;
}

// ---------------------------------------------------------------------------
// Stage 1 (ROUND-14 EXACT): value proj + off/attn proj, heterogeneous
// persistent launch. 256 blocks x 1024 thr, B in VGPRs, A dbuf in LDS,
// 1-deep prefetch, one __syncthreads per tile, swapped-MFMA packed stores.
//   blocks 0..142   : enc @ W_val^T   -> vflat bf16
//   blocks 143..255 : hidden @ [W_off;W_attn]^T -> proj f16 [M][96]
// ---------------------------------------------------------------------------
__global__ __launch_bounds__(1024) void stage1(
    const float* __restrict__ enc, const float* __restrict__ Wval,
    const float* __restrict__ bval, unsigned short* __restrict__ vflat,
    const float* __restrict__ hidden, const float* __restrict__ Woff,
    const float* __restrict__ Wattn, const float* __restrict__ boff,
    const float* __restrict__ battn, unsigned short* __restrict__ proj)
{
    __shared__ __align__(16) short As[2][32 * 256];   // 2 x 16 KB

    const int tid  = threadIdx.x;
    const int lane = tid & 63, w = tid >> 6;
    const int l15  = lane & 15, l4 = lane >> 4;
    const int arow = tid >> 5, ak = (tid & 31) * 8;

    constexpr int NV = 143, NJ = 113;

    if (blockIdx.x < NV) {
        // ---------------- value projection ----------------
        const int n = w * 16 + l15;          // this lane's WEIGHT row
        short8 breg[8];
#pragma unroll
        for (int ks = 0; ks < 8; ++ks) {
            const float* s = &Wval[(size_t)n * K + ks * 32 + l4 * 8];
            breg[ks] = cvt8(*reinterpret_cast<const float4*>(s),
                            *reinterpret_cast<const float4*>(s + 4));
        }
        const int nbase = w * 16 + l4 * 4;
        const float4 bias4 = *reinterpret_cast<const float4*>(&bval[nbase]);
        const int h = w >> 1;                // nbase>>5, uniform per wave
        const int dd0 = nbase & 31;

        int t = blockIdx.x;
        float4 fa0, fa1;
        auto lda = [&](int tt) {
            const float* s = &enc[(size_t)(tt * 32 + arow) * K + ak];
            fa0 = *reinterpret_cast<const float4*>(s);
            fa1 = *reinterpret_cast<const float4*>(s + 4);
        };
        lda(t);
        lds_st16s(As[0], arow, 256, ak, cvt8(fa0, fa1));
        __syncthreads();
        int cur = 0;
        for (; t < NTILES; t += NV) {
            const bool more = (t + NV < NTILES);
            if (more) lda(t + NV);            // overlaps MFMA below

            f32x4 acc0 = {0.f, 0.f, 0.f, 0.f}, acc1 = {0.f, 0.f, 0.f, 0.f};
#pragma unroll
            for (int ks = 0; ks < 8; ++ks) {
                const int kc = ks * 32 + l4 * 8;
                const short8 a0 = lds_ld16s(As[cur], l15, 256, kc);
                const short8 a1 = lds_ld16s(As[cur], 16 + l15, 256, kc);
                acc0 = __builtin_amdgcn_mfma_f32_16x16x32_bf16(breg[ks], a0, acc0, 0, 0, 0);
                acc1 = __builtin_amdgcn_mfma_f32_16x16x32_bf16(breg[ks], a1, acc1, 0, 0, 0);
            }
            const int m0 = t * 32;
            {
                const int m = m0 + l15;
                const int b_ = m / S, s_ = m - b_ * S;
                ushort4p pk;
                pk.x = f2bf(acc0[0] + bias4.x);
                pk.y = f2bf(acc0[1] + bias4.y);
                pk.z = f2bf(acc0[2] + bias4.z);
                pk.w = f2bf(acc0[3] + bias4.w);
                *reinterpret_cast<ushort4p*>(
                    &vflat[(((size_t)(b_ * NH + h)) * S + s_) * DH + dd0]) = pk;
            }
            {
                const int m = m0 + 16 + l15;
                const int b_ = m / S, s_ = m - b_ * S;
                ushort4p pk;
                pk.x = f2bf(acc1[0] + bias4.x);
                pk.y = f2bf(acc1[1] + bias4.y);
                pk.z = f2bf(acc1[2] + bias4.z);
                pk.w = f2bf(acc1[3] + bias4.w);
                *reinterpret_cast<ushort4p*>(
                    &vflat[(((size_t)(b_ * NH + h)) * S + s_) * DH + dd0]) = pk;
            }
            if (more) lds_st16s(As[cur ^ 1], arow, 256, ak, cvt8(fa0, fa1));
            __syncthreads();
            cur ^= 1;
        }
    } else {
        // ---------------- off+attn projection ----------------
        const int nf = w >> 1, mh = w & 1;   // waves 0..11 compute
        const int n = nf * 16 + l15;         // lane's weight row (0..95, w<12)
        short8 breg[8];
        float4 bias4 = {0.f, 0.f, 0.f, 0.f};
        const int nbase = nf * 16 + l4 * 4;  // output n-range after swap
        if (w < 12) {
#pragma unroll
            for (int ks = 0; ks < 8; ++ks) {
                const float* s = (n < 64)
                    ? &Woff[(size_t)n * K + ks * 32 + l4 * 8]
                    : &Wattn[(size_t)(n - 64) * K + ks * 32 + l4 * 8];
                breg[ks] = cvt8(*reinterpret_cast<const float4*>(s),
                                *reinterpret_cast<const float4*>(s + 4));
            }
            bias4 = (nf < 4)
                ? *reinterpret_cast<const float4*>(&boff[nbase])
                : *reinterpret_cast<const float4*>(&battn[nbase - 64]);
        }

        int t = blockIdx.x - NV;
        float4 fa0, fa1;
        auto lda = [&](int tt) {
            const float* s = &hidden[(size_t)(tt * 32 + arow) * K + ak];
            fa0 = *reinterpret_cast<const float4*>(s);
            fa1 = *reinterpret_cast<const float4*>(s + 4);
        };
        lda(t);
        lds_st16s(As[0], arow, 256, ak, cvt8(fa0, fa1));
        __syncthreads();
        int cur = 0;
        for (; t < NTILES; t += NJ) {
            const bool more = (t + NJ < NTILES);
            if (more) lda(t + NJ);

            if (w < 12) {
                f32x4 acc = {0.f, 0.f, 0.f, 0.f};
#pragma unroll
                for (int ks = 0; ks < 8; ++ks) {
                    const int kc = ks * 32 + l4 * 8;
                    const short8 a = lds_ld16s(As[cur], mh * 16 + l15, 256, kc);
                    acc = __builtin_amdgcn_mfma_f32_16x16x32_bf16(breg[ks], a, acc, 0, 0, 0);
                }
                const int m = t * 32 + mh * 16 + l15;
                ushort4p pk;
                pk.x = f2h(acc[0] + bias4.x);
                pk.y = f2h(acc[1] + bias4.y);
                pk.z = f2h(acc[2] + bias4.z);
                pk.w = f2h(acc[3] + bias4.w);
                *reinterpret_cast<ushort4p*>(&proj[(size_t)m * 96 + nbase]) = pk;
            }
            if (more) lds_st16s(As[cur ^ 1], arow, 256, ak, cvt8(fa0, fa1));
            __syncthreads();
            cur ^= 1;
        }
    }
}

// ---------------------------------------------------------------------------
// Kernel S: bilinear sampling + attention aggregation.
// 4 lanes per (b,h,q) group; lane owns 8 d-elements (16B gathers).
// NEW (isolated change vs R14): p-loop split into two no-unroll halves so
// only 2 points' cidx/cw are live at once (~16 VGPR vs 32) -> kernel drops
// under the 64-VGPR occupancy step -> 8 waves/SIMD hide L2 gather latency.
// 5000 blocks, XCD-swizzled (4 contiguous (b,h) slices per XCD).
// ---------------------------------------------------------------------------
__global__ __launch_bounds__(256) void sample_agg(
    const unsigned short* __restrict__ vflat,  // [B*NH][S][DH] bf16
    const unsigned short* __restrict__ proj,   // [M][96] f16
    const float* __restrict__ ref,             // [M][2]
    unsigned short* __restrict__ tmp)          // [M][256] bf16
{
    const int nblk = gridDim.x;                // 5000, %8 == 0
    const int cpx  = nblk >> 3;
    const int swz  = (blockIdx.x & 7) * cpx + (blockIdx.x >> 3);

    const int lg   = threadIdx.x >> 2;   // 0..63
    const int lane = threadIdx.x & 3;
    const int d0   = lane * 8;

    const int g  = swz * 64 + lg;
    const int q  = g % Q;
    const int bh = g / Q;
    const int b  = bh >> 3;
    const int h  = bh & 7;

    const size_t bq = (size_t)b * Q + q;
    const float refx = ref[bq * 2 + 0];
    const float refy = ref[bq * 2 + 1];
    const unsigned short* pr = proj + bq * 96;

    // softmax -> ap[p]
    float ap[NP];
    {
        float l[NP];
#pragma unroll
        for (int p = 0; p < NP; ++p) l[p] = h2f(pr[64 + h * 4 + p]);
        const float mx = fmaxf(fmaxf(l[0], l[1]), fmaxf(l[2], l[3]));
        float esum = 0.f;
#pragma unroll
        for (int p = 0; p < NP; ++p) { ap[p] = __expf(l[p] - mx); esum += ap[p]; }
        const float inv = 1.f / esum;
#pragma unroll
        for (int p = 0; p < NP; ++p) ap[p] *= inv;
    }

    const unsigned short* vbase = vflat + (size_t)bh * (S * DH);

    float o[8];
#pragma unroll
    for (int j = 0; j < 8; ++j) o[j] = 0.f;

#pragma unroll 1
    for (int pp = 0; pp < 2; ++pp) {
        int   cidx[2][4];
        float cwv[2][4];
#pragma unroll
        for (int pi = 0; pi < 2; ++pi) {
            const int p = pp * 2 + pi;
            const float ox = h2f(pr[h * 8 + p * 2 + 0]);
            const float oy = h2f(pr[h * 8 + p * 2 + 1]);
            const float x = fmaf(refx, (float)WW, ox) - 0.5f;
            const float y = fmaf(refy, (float)HH, oy) - 0.5f;
            const float x0f = floorf(x), y0f = floorf(y);
            const float wx1 = x - x0f, wx0 = 1.f - wx1;
            const float wy1 = y - y0f, wy0 = 1.f - wy1;
            const int x0 = (int)x0f, y0 = (int)y0f;
            const bool vx0 = (x0 >= 0) && (x0 < WW);
            const bool vx1 = (x0 + 1 >= 0) && (x0 + 1 < WW);
            const bool vy0 = (y0 >= 0) && (y0 < HH);
            const bool vy1 = (y0 + 1 >= 0) && (y0 + 1 < HH);
            const int xi0 = min(max(x0, 0), WW - 1);
            const int xi1 = min(max(x0 + 1, 0), WW - 1);
            const int yi0 = min(max(y0, 0), HH - 1);
            const int yi1 = min(max(y0 + 1, 0), HH - 1);
            const float a = ap[p];
            cwv[pi][0] = a * wx0 * wy0 * ((vx0 && vy0) ? 1.f : 0.f);
            cwv[pi][1] = a * wx1 * wy0 * ((vx1 && vy0) ? 1.f : 0.f);
            cwv[pi][2] = a * wx0 * wy1 * ((vx0 && vy1) ? 1.f : 0.f);
            cwv[pi][3] = a * wx1 * wy1 * ((vx1 && vy1) ? 1.f : 0.f);
            cidx[pi][0] = (yi0 * WW + xi0) * DH + d0;
            cidx[pi][1] = (yi0 * WW + xi1) * DH + d0;
            cidx[pi][2] = (yi1 * WW + xi0) * DH + d0;
            cidx[pi][3] = (yi1 * WW + xi1) * DH + d0;
        }
#pragma unroll
        for (int pi = 0; pi < 2; ++pi) {
#pragma unroll
            for (int c = 0; c < 4; ++c) {
                const short8 v = *reinterpret_cast<const short8*>(&vbase[cidx[pi][c]]);
                const float wgt = cwv[pi][c];
#pragma unroll
                for (int j = 0; j < 8; ++j)
                    o[j] = fmaf(wgt, bf2f((unsigned short)v[j]), o[j]);
            }
        }
    }

    short8 ov;
#pragma unroll
    for (int j = 0; j < 8; ++j) ov[j] = (short)f2bf(o[j]);
    *reinterpret_cast<short8*>(&tmp[bq * 256 + h * 32 + d0]) = ov;
}

// ---------------------------------------------------------------------------
// Kernel O: out projection (ROUND-14 EXACT): 256 blocks x 1024 thr,
// W in VGPRs, A dbuf in LDS, 1-deep prefetch, __syncthreads per tile,
// swapped-MFMA packed f32x4 stores.
// ---------------------------------------------------------------------------
__global__ __launch_bounds__(1024) void out_proj(
    const unsigned short* __restrict__ tmp, const float* __restrict__ Wo,
    const float* __restrict__ bo, float* __restrict__ out)
{
    __shared__ __align__(16) short As[2][32 * 256];   // 2 x 16 KB

    const int tid  = threadIdx.x;
    const int lane = tid & 63, w = tid >> 6;
    const int l15  = lane & 15, l4 = lane >> 4;
    const int arow = tid >> 5, ak = (tid & 31) * 8;

    const int n = w * 16 + l15;               // lane's weight row
    short8 breg[8];
#pragma unroll
    for (int ks = 0; ks < 8; ++ks) {
        const float* s = &Wo[(size_t)n * K + ks * 32 + l4 * 8];
        breg[ks] = cvt8(*reinterpret_cast<const float4*>(s),
                        *reinterpret_cast<const float4*>(s + 4));
    }
    const int nbase = w * 16 + l4 * 4;        // output n-range after swap
    const float4 bias4 = *reinterpret_cast<const float4*>(&bo[nbase]);

    int t = blockIdx.x;
    short8 sa;
    auto lda = [&](int tt) {
        sa = *reinterpret_cast<const short8*>(&tmp[(size_t)(tt * 32 + arow) * K + ak]);
    };
    lda(t);
    lds_st16s(As[0], arow, 256, ak, sa);
    __syncthreads();
    int cur = 0;
    for (; t < NTILES; t += 256) {
        const bool more = (t + 256 < NTILES);
        if (more) lda(t + 256);

        f32x4 acc0 = {0.f, 0.f, 0.f, 0.f}, acc1 = {0.f, 0.f, 0.f, 0.f};
#pragma unroll
        for (int ks = 0; ks < 8; ++ks) {
            const int kc = ks * 32 + l4 * 8;
            const short8 a0 = lds_ld16s(As[cur], l15, 256, kc);
            const short8 a1 = lds_ld16s(As[cur], 16 + l15, 256, kc);
            acc0 = __builtin_amdgcn_mfma_f32_16x16x32_bf16(breg[ks], a0, acc0, 0, 0, 0);
            acc1 = __builtin_amdgcn_mfma_f32_16x16x32_bf16(breg[ks], a1, acc1, 0, 0, 0);
        }
        const int m0 = t * 32;
        {
            const int m = m0 + l15;
            float4 pv;
            pv.x = acc0[0] + bias4.x; pv.y = acc0[1] + bias4.y;
            pv.z = acc0[2] + bias4.z; pv.w = acc0[3] + bias4.w;
            *reinterpret_cast<float4*>(&out[(size_t)m * K + nbase]) = pv;
        }
        {
            const int m = m0 + 16 + l15;
            float4 pv;
            pv.x = acc1[0] + bias4.x; pv.y = acc1[1] + bias4.y;
            pv.z = acc1[2] + bias4.z; pv.w = acc1[3] + bias4.w;
            *reinterpret_cast<float4*>(&out[(size_t)m * K + nbase]) = pv;
        }
        if (more) lds_st16s(As[cur ^ 1], arow, 256, ak, sa);
        __syncthreads();
        cur ^= 1;
    }
}

// ---------------------------------------------------------------------------
extern "C" void kernel_launch(void* const* d_in, const int* in_sizes, int n_in,
                              void* d_out, int out_size, void* d_ws, size_t ws_size,
                              hipStream_t stream)
{
    const float* hidden = (const float*)d_in[0];
    const float* enc    = (const float*)d_in[1];
    const float* refp   = (const float*)d_in[2];
    const float* W_off  = (const float*)d_in[4];
    const float* b_off  = (const float*)d_in[5];
    const float* W_attn = (const float*)d_in[6];
    const float* b_attn = (const float*)d_in[7];
    const float* W_val  = (const float*)d_in[8];
    const float* b_val  = (const float*)d_in[9];
    const float* W_out  = (const float*)d_in[10];
    const float* b_out  = (const float*)d_in[11];
    float* out = (float*)d_out;

    // workspace (u16 elements): vflat | proj | tmp
    unsigned short* vflat = (unsigned short*)d_ws;     // 10,240,000
    unsigned short* proj  = vflat + (size_t)10240000;  //  3,840,000
    unsigned short* tmp   = proj + (size_t)3840000;    // 10,240,000

    // 1) value proj (143 blocks) + off/attn proj (113 blocks), reg-B persistent
    stage1<<<256, 1024, 0, stream>>>(
        enc, W_val, b_val, vflat, hidden, W_off, W_attn, b_off, b_attn, proj);

    // 2) bilinear sampling + softmax aggregation -> tmp bf16 [M][256]
    sample_agg<<<5000, 256, 0, stream>>>(vflat, proj, refp, tmp);

    // 3) out projection (reg-B persistent, A dbuf, packed f32x4 stores) -> f32
    out_proj<<<256, 1024, 0, stream>>>(tmp, W_out, b_out, out);
}

// Round 20
// 71.841 us; speedup vs baseline: 1.8722x; 1.0216x over previous
//
#include <hip/hip_runtime.h>

constexpr int HH = 100;
constexpr int WW = 100;
constexpr int NH = 8;
constexpr int NP = 4;
constexpr int B  = 4;
constexpr int Q  = HH * WW;   // 10000
constexpr int S  = Q;
constexpr int K  = 256;
constexpr int DH = 32;
constexpr int M  = B * Q;     // 40000
constexpr int NTILES = M / 32; // 1250

typedef __attribute__((ext_vector_type(8))) short short8;
typedef __attribute__((ext_vector_type(4))) float f32x4;

struct __align__(8) ushort4p { unsigned short x, y, z, w; };

__device__ inline unsigned short f2bf(float f) {
    unsigned u = __builtin_bit_cast(unsigned, f);
    u += 0x7fffu + ((u >> 16) & 1u);          // RNE
    return (unsigned short)(u >> 16);
}
__device__ inline float bf2f(unsigned short h) {
    return __builtin_bit_cast(float, ((unsigned)h) << 16);
}
__device__ inline unsigned short f2h(float f) {
    _Float16 h = (_Float16)f;
    return __builtin_bit_cast(unsigned short, h);
}
__device__ inline float h2f(unsigned short u) {
    return (float)__builtin_bit_cast(_Float16, u);
}

// Non-draining barrier: waits LDS ops only (cross-wave visibility of the
// ds_writes); outstanding global stores and prefetch loads stay in flight.
__device__ inline void softbar() {
    asm volatile("s_waitcnt lgkmcnt(0)" ::: "memory");
    __builtin_amdgcn_s_barrier();
}

// LDS bf16 tile helpers (16B-chunk XOR swizzle: chunk ^= row&7).
__device__ inline void lds_st16s(short* base, int row, int stride, int kcol, short8 v) {
    *reinterpret_cast<short8*>(&base[row * stride + (kcol ^ ((row & 7) << 3))]) = v;
}
__device__ inline short8 lds_ld16s(const short* base, int row, int stride, int kcol) {
    return *reinterpret_cast<const short8*>(&base[row * stride + (kcol ^ ((row & 7) << 3))]);
}

__device__ inline short8 cvt8(float4 a, float4 b) {
    short8 r;
    r[0] = (short)f2bf(a.x); r[1] = (short)f2bf(a.y);
    r[2] = (short)f2bf(a.z); r[3] = (short)f2bf(a.w);
    r[4] = (short)f2bf(b.x); r[5] = (short)f2bf(b.y);
    r[6] = (short)f2bf(b.z); r[7] = (short)f2bf(b.w);
    return r;
}

// ---------------------------------------------------------------------------
// Stage 1 (R14 + softbar): value proj + off/attn proj, heterogeneous
// persistent launch. 256 blocks x 1024 thr, B in VGPRs, A dbuf in LDS,
// 1-deep prefetch, swapped-MFMA packed stores. The ONLY change vs R14:
// steady-state barrier is lgkmcnt-only (no vmcnt(0) drain of the epilogue
// stores + prefetch loads).
//   blocks 0..142   : enc @ W_val^T   -> vflat bf16
//   blocks 143..255 : hidden @ [W_off;W_attn]^T -> proj f16 [M][96]
// ---------------------------------------------------------------------------
__global__ __launch_bounds__(1024) void stage1(
    const float* __restrict__ enc, const float* __restrict__ Wval,
    const float* __restrict__ bval, unsigned short* __restrict__ vflat,
    const float* __restrict__ hidden, const float* __restrict__ Woff,
    const float* __restrict__ Wattn, const float* __restrict__ boff,
    const float* __restrict__ battn, unsigned short* __restrict__ proj)
{
    __shared__ __align__(16) short As[2][32 * 256];   // 2 x 16 KB

    const int tid  = threadIdx.x;
    const int lane = tid & 63, w = tid >> 6;
    const int l15  = lane & 15, l4 = lane >> 4;
    const int arow = tid >> 5, ak = (tid & 31) * 8;

    constexpr int NV = 143, NJ = 113;

    if (blockIdx.x < NV) {
        // ---------------- value projection ----------------
        const int n = w * 16 + l15;          // this lane's WEIGHT row
        short8 breg[8];
#pragma unroll
        for (int ks = 0; ks < 8; ++ks) {
            const float* s = &Wval[(size_t)n * K + ks * 32 + l4 * 8];
            breg[ks] = cvt8(*reinterpret_cast<const float4*>(s),
                            *reinterpret_cast<const float4*>(s + 4));
        }
        const int nbase = w * 16 + l4 * 4;
        const float4 bias4 = *reinterpret_cast<const float4*>(&bval[nbase]);
        const int h = w >> 1;                // nbase>>5, uniform per wave
        const int dd0 = nbase & 31;

        int t = blockIdx.x;
        float4 fa0, fa1;
        auto lda = [&](int tt) {
            const float* s = &enc[(size_t)(tt * 32 + arow) * K + ak];
            fa0 = *reinterpret_cast<const float4*>(s);
            fa1 = *reinterpret_cast<const float4*>(s + 4);
        };
        lda(t);
        lds_st16s(As[0], arow, 256, ak, cvt8(fa0, fa1));
        __syncthreads();
        int cur = 0;
        for (; t < NTILES; t += NV) {
            const bool more = (t + NV < NTILES);
            if (more) lda(t + NV);            // overlaps MFMA below

            f32x4 acc0 = {0.f, 0.f, 0.f, 0.f}, acc1 = {0.f, 0.f, 0.f, 0.f};
#pragma unroll
            for (int ks = 0; ks < 8; ++ks) {
                const int kc = ks * 32 + l4 * 8;
                const short8 a0 = lds_ld16s(As[cur], l15, 256, kc);
                const short8 a1 = lds_ld16s(As[cur], 16 + l15, 256, kc);
                acc0 = __builtin_amdgcn_mfma_f32_16x16x32_bf16(breg[ks], a0, acc0, 0, 0, 0);
                acc1 = __builtin_amdgcn_mfma_f32_16x16x32_bf16(breg[ks], a1, acc1, 0, 0, 0);
            }
            const int m0 = t * 32;
            {
                const int m = m0 + l15;
                const int b_ = m / S, s_ = m - b_ * S;
                ushort4p pk;
                pk.x = f2bf(acc0[0] + bias4.x);
                pk.y = f2bf(acc0[1] + bias4.y);
                pk.z = f2bf(acc0[2] + bias4.z);
                pk.w = f2bf(acc0[3] + bias4.w);
                *reinterpret_cast<ushort4p*>(
                    &vflat[(((size_t)(b_ * NH + h)) * S + s_) * DH + dd0]) = pk;
            }
            {
                const int m = m0 + 16 + l15;
                const int b_ = m / S, s_ = m - b_ * S;
                ushort4p pk;
                pk.x = f2bf(acc1[0] + bias4.x);
                pk.y = f2bf(acc1[1] + bias4.y);
                pk.z = f2bf(acc1[2] + bias4.z);
                pk.w = f2bf(acc1[3] + bias4.w);
                *reinterpret_cast<ushort4p*>(
                    &vflat[(((size_t)(b_ * NH + h)) * S + s_) * DH + dd0]) = pk;
            }
            if (more) lds_st16s(As[cur ^ 1], arow, 256, ak, cvt8(fa0, fa1));
            softbar();
            cur ^= 1;
        }
    } else {
        // ---------------- off+attn projection ----------------
        const int nf = w >> 1, mh = w & 1;   // waves 0..11 compute
        const int n = nf * 16 + l15;         // lane's weight row (0..95, w<12)
        short8 breg[8];
        float4 bias4 = {0.f, 0.f, 0.f, 0.f};
        const int nbase = nf * 16 + l4 * 4;  // output n-range after swap
        if (w < 12) {
#pragma unroll
            for (int ks = 0; ks < 8; ++ks) {
                const float* s = (n < 64)
                    ? &Woff[(size_t)n * K + ks * 32 + l4 * 8]
                    : &Wattn[(size_t)(n - 64) * K + ks * 32 + l4 * 8];
                breg[ks] = cvt8(*reinterpret_cast<const float4*>(s),
                                *reinterpret_cast<const float4*>(s + 4));
            }
            bias4 = (nf < 4)
                ? *reinterpret_cast<const float4*>(&boff[nbase])
                : *reinterpret_cast<const float4*>(&battn[nbase - 64]);
        }

        int t = blockIdx.x - NV;
        float4 fa0, fa1;
        auto lda = [&](int tt) {
            const float* s = &hidden[(size_t)(tt * 32 + arow) * K + ak];
            fa0 = *reinterpret_cast<const float4*>(s);
            fa1 = *reinterpret_cast<const float4*>(s + 4);
        };
        lda(t);
        lds_st16s(As[0], arow, 256, ak, cvt8(fa0, fa1));
        __syncthreads();
        int cur = 0;
        for (; t < NTILES; t += NJ) {
            const bool more = (t + NJ < NTILES);
            if (more) lda(t + NJ);

            if (w < 12) {
                f32x4 acc = {0.f, 0.f, 0.f, 0.f};
#pragma unroll
                for (int ks = 0; ks < 8; ++ks) {
                    const int kc = ks * 32 + l4 * 8;
                    const short8 a = lds_ld16s(As[cur], mh * 16 + l15, 256, kc);
                    acc = __builtin_amdgcn_mfma_f32_16x16x32_bf16(breg[ks], a, acc, 0, 0, 0);
                }
                const int m = t * 32 + mh * 16 + l15;
                ushort4p pk;
                pk.x = f2h(acc[0] + bias4.x);
                pk.y = f2h(acc[1] + bias4.y);
                pk.z = f2h(acc[2] + bias4.z);
                pk.w = f2h(acc[3] + bias4.w);
                *reinterpret_cast<ushort4p*>(&proj[(size_t)m * 96 + nbase]) = pk;
            }
            if (more) lds_st16s(As[cur ^ 1], arow, 256, ak, cvt8(fa0, fa1));
            softbar();
            cur ^= 1;
        }
    }
}

// ---------------------------------------------------------------------------
// Kernel S: bilinear sampling + attention aggregation (R14 exact).
// 4 lanes per (b,h,q) group; lane owns 8 d-elements (16B gathers).
// 64 groups per 256-thread block; 5000 blocks, XCD-swizzled.
// ---------------------------------------------------------------------------
__global__ __launch_bounds__(256) void sample_agg(
    const unsigned short* __restrict__ vflat,  // [B*NH][S][DH] bf16
    const unsigned short* __restrict__ proj,   // [M][96] f16
    const float* __restrict__ ref,             // [M][2]
    unsigned short* __restrict__ tmp)          // [M][256] bf16
{
    const int nblk = gridDim.x;                // 5000, %8 == 0
    const int cpx  = nblk >> 3;
    const int swz  = (blockIdx.x & 7) * cpx + (blockIdx.x >> 3);

    const int lg   = threadIdx.x >> 2;   // 0..63
    const int lane = threadIdx.x & 3;
    const int d0   = lane * 8;

    const int g  = swz * 64 + lg;
    const int q  = g % Q;
    const int bh = g / Q;
    const int b  = bh >> 3;
    const int h  = bh & 7;

    const size_t bq = (size_t)b * Q + q;
    const float refx = ref[bq * 2 + 0];
    const float refy = ref[bq * 2 + 1];
    const unsigned short* pr = proj + bq * 96;

    float l[NP];
#pragma unroll
    for (int p = 0; p < NP; ++p) l[p] = h2f(pr[64 + h * 4 + p]);
    const float mx = fmaxf(fmaxf(l[0], l[1]), fmaxf(l[2], l[3]));
    float e[NP];
    float esum = 0.f;
#pragma unroll
    for (int p = 0; p < NP; ++p) { e[p] = __expf(l[p] - mx); esum += e[p]; }
    const float inv = 1.f / esum;

    const unsigned short* vbase = vflat + (size_t)bh * (S * DH);

    int   cidx[NP][4];
    float cw[NP][4];
#pragma unroll
    for (int p = 0; p < NP; ++p) {
        const float ox = h2f(pr[h * 8 + p * 2 + 0]);
        const float oy = h2f(pr[h * 8 + p * 2 + 1]);
        const float x = fmaf(refx, (float)WW, ox) - 0.5f;
        const float y = fmaf(refy, (float)HH, oy) - 0.5f;
        const float x0f = floorf(x), y0f = floorf(y);
        const float wx1 = x - x0f, wx0 = 1.f - wx1;
        const float wy1 = y - y0f, wy0 = 1.f - wy1;
        const int x0 = (int)x0f, y0 = (int)y0f;
        const bool vx0 = (x0 >= 0) && (x0 < WW);
        const bool vx1 = (x0 + 1 >= 0) && (x0 + 1 < WW);
        const bool vy0 = (y0 >= 0) && (y0 < HH);
        const bool vy1 = (y0 + 1 >= 0) && (y0 + 1 < HH);
        const int xi0 = min(max(x0, 0), WW - 1);
        const int xi1 = min(max(x0 + 1, 0), WW - 1);
        const int yi0 = min(max(y0, 0), HH - 1);
        const int yi1 = min(max(y0 + 1, 0), HH - 1);
        const float ap = e[p] * inv;
        cw[p][0] = ap * wx0 * wy0 * ((vx0 && vy0) ? 1.f : 0.f);
        cw[p][1] = ap * wx1 * wy0 * ((vx1 && vy0) ? 1.f : 0.f);
        cw[p][2] = ap * wx0 * wy1 * ((vx0 && vy1) ? 1.f : 0.f);
        cw[p][3] = ap * wx1 * wy1 * ((vx1 && vy1) ? 1.f : 0.f);
        cidx[p][0] = (yi0 * WW + xi0) * DH + d0;
        cidx[p][1] = (yi0 * WW + xi1) * DH + d0;
        cidx[p][2] = (yi1 * WW + xi0) * DH + d0;
        cidx[p][3] = (yi1 * WW + xi1) * DH + d0;
    }

    float o[8];
#pragma unroll
    for (int j = 0; j < 8; ++j) o[j] = 0.f;
#pragma unroll
    for (int p = 0; p < NP; ++p) {
#pragma unroll
        for (int c = 0; c < 4; ++c) {
            const short8 v = *reinterpret_cast<const short8*>(&vbase[cidx[p][c]]);
            const float wgt = cw[p][c];
#pragma unroll
            for (int j = 0; j < 8; ++j)
                o[j] = fmaf(wgt, bf2f((unsigned short)v[j]), o[j]);
        }
    }

    short8 ov;
#pragma unroll
    for (int j = 0; j < 8; ++j) ov[j] = (short)f2bf(o[j]);
    *reinterpret_cast<short8*>(&tmp[bq * 256 + h * 32 + d0]) = ov;
}

// ---------------------------------------------------------------------------
// Kernel O: out projection (R14 + softbar): 256 blocks x 1024 thr,
// W in VGPRs, A dbuf in LDS, 1-deep prefetch, swapped-MFMA f32x4 stores.
// ---------------------------------------------------------------------------
__global__ __launch_bounds__(1024) void out_proj(
    const unsigned short* __restrict__ tmp, const float* __restrict__ Wo,
    const float* __restrict__ bo, float* __restrict__ out)
{
    __shared__ __align__(16) short As[2][32 * 256];   // 2 x 16 KB

    const int tid  = threadIdx.x;
    const int lane = tid & 63, w = tid >> 6;
    const int l15  = lane & 15, l4 = lane >> 4;
    const int arow = tid >> 5, ak = (tid & 31) * 8;

    const int n = w * 16 + l15;               // lane's weight row
    short8 breg[8];
#pragma unroll
    for (int ks = 0; ks < 8; ++ks) {
        const float* s = &Wo[(size_t)n * K + ks * 32 + l4 * 8];
        breg[ks] = cvt8(*reinterpret_cast<const float4*>(s),
                        *reinterpret_cast<const float4*>(s + 4));
    }
    const int nbase = w * 16 + l4 * 4;        // output n-range after swap
    const float4 bias4 = *reinterpret_cast<const float4*>(&bo[nbase]);

    int t = blockIdx.x;
    short8 sa;
    auto lda = [&](int tt) {
        sa = *reinterpret_cast<const short8*>(&tmp[(size_t)(tt * 32 + arow) * K + ak]);
    };
    lda(t);
    lds_st16s(As[0], arow, 256, ak, sa);
    __syncthreads();
    int cur = 0;
    for (; t < NTILES; t += 256) {
        const bool more = (t + 256 < NTILES);
        if (more) lda(t + 256);

        f32x4 acc0 = {0.f, 0.f, 0.f, 0.f}, acc1 = {0.f, 0.f, 0.f, 0.f};
#pragma unroll
        for (int ks = 0; ks < 8; ++ks) {
            const int kc = ks * 32 + l4 * 8;
            const short8 a0 = lds_ld16s(As[cur], l15, 256, kc);
            const short8 a1 = lds_ld16s(As[cur], 16 + l15, 256, kc);
            acc0 = __builtin_amdgcn_mfma_f32_16x16x32_bf16(breg[ks], a0, acc0, 0, 0, 0);
            acc1 = __builtin_amdgcn_mfma_f32_16x16x32_bf16(breg[ks], a1, acc1, 0, 0, 0);
        }
        const int m0 = t * 32;
        {
            const int m = m0 + l15;
            float4 pv;
            pv.x = acc0[0] + bias4.x; pv.y = acc0[1] + bias4.y;
            pv.z = acc0[2] + bias4.z; pv.w = acc0[3] + bias4.w;
            *reinterpret_cast<float4*>(&out[(size_t)m * K + nbase]) = pv;
        }
        {
            const int m = m0 + 16 + l15;
            float4 pv;
            pv.x = acc1[0] + bias4.x; pv.y = acc1[1] + bias4.y;
            pv.z = acc1[2] + bias4.z; pv.w = acc1[3] + bias4.w;
            *reinterpret_cast<float4*>(&out[(size_t)m * K + nbase]) = pv;
        }
        if (more) lds_st16s(As[cur ^ 1], arow, 256, ak, sa);
        softbar();
        cur ^= 1;
    }
}

// ---------------------------------------------------------------------------
extern "C" void kernel_launch(void* const* d_in, const int* in_sizes, int n_in,
                              void* d_out, int out_size, void* d_ws, size_t ws_size,
                              hipStream_t stream)
{
    const float* hidden = (const float*)d_in[0];
    const float* enc    = (const float*)d_in[1];
    const float* refp   = (const float*)d_in[2];
    const float* W_off  = (const float*)d_in[4];
    const float* b_off  = (const float*)d_in[5];
    const float* W_attn = (const float*)d_in[6];
    const float* b_attn = (const float*)d_in[7];
    const float* W_val  = (const float*)d_in[8];
    const float* b_val  = (const float*)d_in[9];
    const float* W_out  = (const float*)d_in[10];
    const float* b_out  = (const float*)d_in[11];
    float* out = (float*)d_out;

    // workspace (u16 elements): vflat | proj | tmp
    unsigned short* vflat = (unsigned short*)d_ws;     // 10,240,000
    unsigned short* proj  = vflat + (size_t)10240000;  //  3,840,000
    unsigned short* tmp   = proj + (size_t)3840000;    // 10,240,000

    // 1) value proj (143 blocks) + off/attn proj (113 blocks), reg-B persistent
    stage1<<<256, 1024, 0, stream>>>(
        enc, W_val, b_val, vflat, hidden, W_off, W_attn, b_off, b_attn, proj);

    // 2) bilinear sampling + softmax aggregation -> tmp bf16 [M][256]
    sample_agg<<<5000, 256, 0, stream>>>(vflat, proj, refp, tmp);

    // 3) out projection (reg-B persistent, A dbuf, softbar) -> f32
    out_proj<<<256, 1024, 0, stream>>>(tmp, W_out, b_out, out);
}